// Round 5
// baseline (245.744 us; speedup 1.0000x reference)
//
#include <hip/hip_runtime.h>

#define OUT 7
#define NCH 256
#define NROI 512
#define NS 14            // bilinear samples per axis (7 bins x 2)
#define NT 28            // tap slots per axis (lo/hi per sample) -- data-independent bound
#define CCH 32           // channels per block
#define CPAD 34          // bf16 elems per tap cell: 32 ch + 2 pad = 17 words (odd stride)
#define TPR (NCH * OUT * OUT)   // 12544 outputs per RoI

__device__ __forceinline__ float rfl_f(float v) {
    return __int_as_float(__builtin_amdgcn_readfirstlane(__float_as_int(v)));
}

__device__ __forceinline__ unsigned short f2bf_rne(float f) {
    unsigned int u = __float_as_uint(f);
    u += 0x7FFFu + ((u >> 16) & 1u);   // round-to-nearest-even
    return (unsigned short)(u >> 16);
}

// Block = (RoI, 32-channel chunk). Phase 1: one wave builds the per-axis tap
// LUT (28 row indices, 28 col indices, 14 ly/lx + validity). Phase 2: stage
// the exact 28x28 tap grid for 32 channels into LDS (bf16) via row gathers.
// Phase 3: 49 px x 16 channel-pairs pooled from LDS. Phase 4: repack + store.
__global__ __launch_bounds__(256, 3) void roi_align_tap_kernel(
        const float* __restrict__ f0, const float* __restrict__ f1,
        const float* __restrict__ f2, const float* __restrict__ f3,
        const float* __restrict__ boxes, float* __restrict__ out) {
    __shared__ unsigned short sm[NT * NT * CPAD];   // 53,312 B
    __shared__ int   rowIdx[NT];
    __shared__ int   colIdx[NT];
    __shared__ float lyS[NS], vyS[NS], lxS[NS], vxS[NS];

    int blk = blockIdx.x;
    int r   = blk >> 3;          // RoI id
    int q   = blk & 7;           // 32-channel chunk
    int tid = (int)threadIdx.x;

    // ---------------- wave-uniform RoI meta ----------------
    float bx1 = rfl_f(boxes[r * 4 + 0]);
    float by1 = rfl_f(boxes[r * 4 + 1]);
    float bx2 = rfl_f(boxes[r * 4 + 2]);
    float by2 = rfl_f(boxes[r * 4 + 3]);

    float area = (bx2 - bx1) * (by2 - by1);
    float s    = sqrtf(area);
    float lvl  = floorf(4.0f + log2f(s * (1.0f / 224.0f) + 1e-6f));
    lvl        = fminf(fmaxf(lvl, 2.0f), 5.0f);
    int level  = __builtin_amdgcn_readfirstlane((int)lvl - 2);

    const float* f; int H; float scale;
    switch (level) {
        case 0:  f = f0; H = 200; scale = 0.25f;    break;
        case 1:  f = f1; H = 100; scale = 0.125f;   break;
        case 2:  f = f2; H = 50;  scale = 0.0625f;  break;
        default: f = f3; H = 25;  scale = 0.03125f; break;
    }
    float Hf = (float)H;

    float x1 = bx1 * scale, y1 = by1 * scale;
    float roi_w = fmaxf(bx2 * scale - x1, 1.0f);
    float roi_h = fmaxf(by2 * scale - y1, 1.0f);
    float bin_w = roi_w * (1.0f / OUT);
    float bin_h = roi_h * (1.0f / OUT);

    // ---------------- phase 1: tap LUT (wave 0) ----------------
    if (tid < NS) {                       // y samples
        int ph = tid >> 1, iy = tid & 1;
        float y = y1 + ((float)ph + (iy ? 0.75f : 0.25f)) * bin_h;
        float v = (y >= -1.0f && y <= Hf) ? 0.5f : 0.0f;   // m = vy*vx = 0.25
        y = fmaxf(y, 0.0f);
        int yl = (int)y, yh;
        float ly;
        if (yl >= H - 1) { yl = H - 1; yh = H - 1; ly = 0.0f; }
        else             { yh = yl + 1; ly = y - (float)yl; }
        lyS[tid] = ly; vyS[tid] = v;
        rowIdx[2 * tid]     = yl;
        rowIdx[2 * tid + 1] = yh;
    } else if (tid >= 32 && tid < 32 + NS) {   // x samples
        int t = tid - 32;
        int pw = t >> 1, ix = t & 1;
        float x = x1 + ((float)pw + (ix ? 0.75f : 0.25f)) * bin_w;
        float v = (x >= -1.0f && x <= Hf) ? 0.5f : 0.0f;
        x = fmaxf(x, 0.0f);
        int xl = (int)x, xh;
        float lx;
        if (xl >= H - 1) { xl = H - 1; xh = H - 1; lx = 0.0f; }
        else             { xh = xl + 1; lx = x - (float)xl; }
        lxS[t] = lx; vxS[t] = v;
        colIdx[2 * t]     = xl;
        colIdx[2 * t + 1] = xh;
    }
    __syncthreads();

    // ---------------- phase 2: stage 28x28x32 tap grid ----------------
    int bidx = r >> 8;   // 256 RoIs per batch image
    const float* plane = f + (size_t)(bidx * NCH + q * CCH) * (size_t)(H * H);
    size_t HH = (size_t)(H * H);

    int lane = tid & 63;
    int wave = tid >> 6;
    int j    = lane & 31;        // col slot
    int ch2  = lane >> 5;        // channel half (0: ch 0-15, 1: ch 16-31)
    bool jok = (j < NT);
    int col  = jok ? colIdx[j] : 0;

#pragma unroll
    for (int t = 0; t < 7; ++t) {
        int i = wave * 7 + t;                 // row slot 0..27
        size_t rbase = (size_t)rowIdx[i] * (size_t)H + (size_t)col;
        unsigned short* smrow = sm + (i * NT + j) * CPAD;
#pragma unroll 4
        for (int cc = 0; cc < 16; ++cc) {
            int ch = ch2 * 16 + cc;
            float v = 0.0f;
            if (jok) v = plane[(size_t)ch * HH + rbase];
            if (jok) smrow[ch] = f2bf_rne(v);
        }
    }
    __syncthreads();

    // ---------------- phase 3: pool 49 px x 16 channel-pairs ----------------
    const unsigned int* smw = (const unsigned int*)sm;
    float accx[4], accy[4];
#pragma unroll
    for (int i = 0; i < 4; ++i) { accx[i] = 0.0f; accy[i] = 0.0f; }

#pragma unroll
    for (int i = 0; i < 4; ++i) {
        int o = tid + 256 * i;
        if (o < 784) {
            int px = o >> 4, cp = o & 15;
            int ph = px / 7, pw = px - ph * 7;
            float ax = 0.0f, ay = 0.0f;
#pragma unroll
            for (int iy = 0; iy < 2; ++iy) {
                int sy = ph * 2 + iy;
                float ly = lyS[sy], hy = 1.0f - ly;
                float vy = vyS[sy];
                int r0 = (2 * sy) * NT;
                int r1 = (2 * sy + 1) * NT;
#pragma unroll
                for (int ix = 0; ix < 2; ++ix) {
                    int sx = pw * 2 + ix;
                    float lx = lxS[sx], hx = 1.0f - lx;
                    float m  = vy * vxS[sx];       // 0.25 if valid else 0
                    int c0 = 2 * sx, c1 = 2 * sx + 1;
                    unsigned int u00 = smw[(r0 + c0) * 17 + cp];
                    unsigned int u01 = smw[(r0 + c1) * 17 + cp];
                    unsigned int u10 = smw[(r1 + c0) * 17 + cp];
                    unsigned int u11 = smw[(r1 + c1) * 17 + cp];
                    float w00 = hy * hx * m, w01 = hy * lx * m;
                    float w10 = ly * hx * m, w11 = ly * lx * m;
                    ax = fmaf(w00, __uint_as_float(u00 << 16), ax);
                    ay = fmaf(w00, __uint_as_float(u00 & 0xFFFF0000u), ay);
                    ax = fmaf(w01, __uint_as_float(u01 << 16), ax);
                    ay = fmaf(w01, __uint_as_float(u01 & 0xFFFF0000u), ay);
                    ax = fmaf(w10, __uint_as_float(u10 << 16), ax);
                    ay = fmaf(w10, __uint_as_float(u10 & 0xFFFF0000u), ay);
                    ax = fmaf(w11, __uint_as_float(u11 << 16), ax);
                    ay = fmaf(w11, __uint_as_float(u11 & 0xFFFF0000u), ay);
                }
            }
            accx[i] = ax; accy[i] = ay;
        }
    }
    __syncthreads();   // LDS reads done; reuse sm for output repack

    // ---------------- phase 4: repack via LDS, contiguous store ----------------
    float* smf = (float*)sm;
#pragma unroll
    for (int i = 0; i < 4; ++i) {
        int o = tid + 256 * i;
        if (o < 784) {
            int px = o >> 4, cp = o & 15;
            smf[(cp * 2 + 0) * 49 + px] = accx[i];
            smf[(cp * 2 + 1) * 49 + px] = accy[i];
        }
    }
    __syncthreads();

    float* dst = out + (size_t)r * TPR + (size_t)q * (CCH * 49);
    for (int e = tid; e < CCH * 49; e += 256) dst[e] = smf[e];
}

extern "C" void kernel_launch(void* const* d_in, const int* in_sizes, int n_in,
                              void* d_out, int out_size, void* d_ws, size_t ws_size,
                              hipStream_t stream) {
    const float* f0    = (const float*)d_in[0];
    const float* f1    = (const float*)d_in[1];
    const float* f2    = (const float*)d_in[2];
    const float* f3    = (const float*)d_in[3];
    const float* boxes = (const float*)d_in[4];
    float* out         = (float*)d_out;

    roi_align_tap_kernel<<<NROI * 8, 256, 0, stream>>>(f0, f1, f2, f3, boxes, out);
}

// Round 6
// 182.192 us; speedup vs baseline: 1.3488x; 1.3488x over previous
//
#include <hip/hip_runtime.h>

#define OUT 7
#define NCH 256
#define NROI 512
#define NS 14            // bilinear samples per axis (7 bins x 2)
#define NT 28            // tap slots per axis (lo/hi per sample)
#define CCH 16           // channels per block
#define W9 9             // LDS words per row-slot within a col-slot: 8 cp + 1 pad
#define WPC 253          // LDS words per col-slot: 28*9 + 1 (odd -> conflict-free)
#define TPR (NCH * OUT * OUT)

__device__ __forceinline__ float rfl_f(float v) {
    return __int_as_float(__builtin_amdgcn_readfirstlane(__float_as_int(v)));
}

__device__ __forceinline__ unsigned short f2bf_rne(float f) {
    unsigned int u = __float_as_uint(f);
    u += 0x7FFFu + ((u >> 16) & 1u);   // round-to-nearest-even
    return (unsigned short)(u >> 16);
}

// Block = (RoI, 16-channel chunk). Phase 1: tap LUT. Phase 2: stage the exact
// 28x28 tap grid x16ch into LDS bf16 (loads batched 8-wide for MLP).
// Phase 3: 49 px x 8 channel-pairs pooled from LDS. Phase 4: repack + store.
// LDS word index: colslot*253 + rowslot*9 + cp  (cp = channel pair 0..7).
__global__ __launch_bounds__(256, 4) void roi_align_tap16_kernel(
        const float* __restrict__ f0, const float* __restrict__ f1,
        const float* __restrict__ f2, const float* __restrict__ f3,
        const float* __restrict__ boxes, float* __restrict__ out) {
    __shared__ unsigned short sm[NT * WPC * 2];   // 28,336 B -> 4-5 blocks/CU
    __shared__ int   rowIdx[NT];
    __shared__ int   colIdx[NT];
    __shared__ float lyS[NS], vyS[NS], lxS[NS], vxS[NS];

    int g    = blockIdx.x;
    int xcd  = g & 7;
    int slot = g >> 3;
    int rr   = slot >> 4;
    int q    = slot & 15;          // 16-channel chunk
    int r    = rr * 8 + xcd;       // RoI id: all 16 chunks share g%8 (same XCD)
    int tid  = (int)threadIdx.x;

    // ---------------- wave-uniform RoI meta ----------------
    float bx1 = rfl_f(boxes[r * 4 + 0]);
    float by1 = rfl_f(boxes[r * 4 + 1]);
    float bx2 = rfl_f(boxes[r * 4 + 2]);
    float by2 = rfl_f(boxes[r * 4 + 3]);

    float area = (bx2 - bx1) * (by2 - by1);
    float s    = sqrtf(area);
    float lvl  = floorf(4.0f + log2f(s * (1.0f / 224.0f) + 1e-6f));
    lvl        = fminf(fmaxf(lvl, 2.0f), 5.0f);
    int level  = __builtin_amdgcn_readfirstlane((int)lvl - 2);

    const float* f; int H; float scale;
    switch (level) {
        case 0:  f = f0; H = 200; scale = 0.25f;    break;
        case 1:  f = f1; H = 100; scale = 0.125f;   break;
        case 2:  f = f2; H = 50;  scale = 0.0625f;  break;
        default: f = f3; H = 25;  scale = 0.03125f; break;
    }
    float Hf = (float)H;

    float x1 = bx1 * scale, y1 = by1 * scale;
    float roi_w = fmaxf(bx2 * scale - x1, 1.0f);
    float roi_h = fmaxf(by2 * scale - y1, 1.0f);
    float bin_w = roi_w * (1.0f / OUT);
    float bin_h = roi_h * (1.0f / OUT);

    // ---------------- phase 1: tap LUT ----------------
    if (tid < NS) {                       // y samples
        int ph = tid >> 1, iy = tid & 1;
        float y = y1 + ((float)ph + (iy ? 0.75f : 0.25f)) * bin_h;
        float v = (y >= -1.0f && y <= Hf) ? 0.5f : 0.0f;   // vy*vx = 0.25
        y = fmaxf(y, 0.0f);
        int yl = (int)y, yh;
        float ly;
        if (yl >= H - 1) { yl = H - 1; yh = H - 1; ly = 0.0f; }
        else             { yh = yl + 1; ly = y - (float)yl; }
        lyS[tid] = ly; vyS[tid] = v;
        rowIdx[2 * tid]     = yl;
        rowIdx[2 * tid + 1] = yh;
    } else if (tid >= 32 && tid < 32 + NS) {   // x samples
        int t = tid - 32;
        int pw = t >> 1, ix = t & 1;
        float x = x1 + ((float)pw + (ix ? 0.75f : 0.25f)) * bin_w;
        float v = (x >= -1.0f && x <= Hf) ? 0.5f : 0.0f;
        x = fmaxf(x, 0.0f);
        int xl = (int)x, xh;
        float lx;
        if (xl >= H - 1) { xl = H - 1; xh = H - 1; lx = 0.0f; }
        else             { xh = xl + 1; lx = x - (float)xl; }
        lxS[t] = lx; vxS[t] = v;
        colIdx[2 * t]     = xl;
        colIdx[2 * t + 1] = xh;
    }
    __syncthreads();

    // ---------------- phase 2: stage 28x28x16 tap grid ----------------
    int bidx = r >> 8;   // 256 RoIs per batch image
    size_t HH = (size_t)(H * H);
    const float* plane = f + (size_t)(bidx * NCH + q * CCH) * HH;

    int lane = tid & 63;
    int wave = tid >> 6;
    // lanes 0..27: cols, cg=0 (ch 0..7); lanes 28..55: cols, cg=1 (ch 8..15)
    int  j   = (lane < 28) ? lane : ((lane < 56) ? lane - 28 : lane - 56);
    int  cg  = (lane >= 28 && lane < 56) ? 1 : 0;
    bool act = (lane < 56);
    int  col = colIdx[j];

#pragma unroll
    for (int t = 0; t < 7; ++t) {
        int rs = wave * 7 + t;                     // row slot 0..27
        size_t rbase = (size_t)rowIdx[rs] * (size_t)H + (size_t)col;
        float v[8];
#pragma unroll
        for (int cc = 0; cc < 8; ++cc)             // 8 independent loads
            v[cc] = plane[(size_t)(cg * 8 + cc) * HH + rbase];
        unsigned short* dstp = sm + (j * WPC + rs * W9) * 2 + cg * 8;
#pragma unroll
        for (int cc = 0; cc < 8; ++cc)
            if (act) dstp[cc] = f2bf_rne(v[cc]);
    }
    __syncthreads();

    // ---------------- phase 3: pool 49 px x 8 channel-pairs ----------------
    const unsigned int* smw = (const unsigned int*)sm;
    float accx[2], accy[2];
#pragma unroll
    for (int i = 0; i < 2; ++i) { accx[i] = 0.0f; accy[i] = 0.0f; }

#pragma unroll
    for (int i = 0; i < 2; ++i) {
        int o = tid + 256 * i;
        if (o < 392) {
            int cp = o & 7, px = o >> 3;
            int ph = px / 7, pw = px - ph * 7;
            float ax = 0.0f, ay = 0.0f;
#pragma unroll
            for (int iy = 0; iy < 2; ++iy) {
                int sy = ph * 2 + iy;
                float ly = lyS[sy], hy = 1.0f - ly;
                float vy = vyS[sy];
                int r0 = (2 * sy) * W9 + cp;
                int r1 = r0 + W9;
#pragma unroll
                for (int ix = 0; ix < 2; ++ix) {
                    int sx = pw * 2 + ix;
                    float lx = lxS[sx], hx = 1.0f - lx;
                    float m  = vy * vxS[sx];       // 0.25 if valid else 0
                    int c0 = (2 * sx) * WPC;
                    int c1 = c0 + WPC;
                    unsigned int u00 = smw[c0 + r0];
                    unsigned int u01 = smw[c1 + r0];
                    unsigned int u10 = smw[c0 + r1];
                    unsigned int u11 = smw[c1 + r1];
                    float w00 = hy * hx * m, w01 = hy * lx * m;
                    float w10 = ly * hx * m, w11 = ly * lx * m;
                    ax = fmaf(w00, __uint_as_float(u00 << 16), ax);
                    ay = fmaf(w00, __uint_as_float(u00 & 0xFFFF0000u), ay);
                    ax = fmaf(w01, __uint_as_float(u01 << 16), ax);
                    ay = fmaf(w01, __uint_as_float(u01 & 0xFFFF0000u), ay);
                    ax = fmaf(w10, __uint_as_float(u10 << 16), ax);
                    ay = fmaf(w10, __uint_as_float(u10 & 0xFFFF0000u), ay);
                    ax = fmaf(w11, __uint_as_float(u11 << 16), ax);
                    ay = fmaf(w11, __uint_as_float(u11 & 0xFFFF0000u), ay);
                }
            }
            accx[i] = ax; accy[i] = ay;
        }
    }
    __syncthreads();   // LDS reads done; reuse sm for output repack

    // ---------------- phase 4: repack via LDS, contiguous store ----------------
    float* smf = (float*)sm;
#pragma unroll
    for (int i = 0; i < 2; ++i) {
        int o = tid + 256 * i;
        if (o < 392) {
            int cp = o & 7, px = o >> 3;
            smf[(cp * 2 + 0) * 49 + px] = accx[i];  // even channel (low ushort)
            smf[(cp * 2 + 1) * 49 + px] = accy[i];  // odd channel (high ushort)
        }
    }
    __syncthreads();

    float* dst = out + (size_t)r * TPR + (size_t)q * (CCH * 49);
    for (int e = tid; e < CCH * 49; e += 256) dst[e] = smf[e];
}

extern "C" void kernel_launch(void* const* d_in, const int* in_sizes, int n_in,
                              void* d_out, int out_size, void* d_ws, size_t ws_size,
                              hipStream_t stream) {
    const float* f0    = (const float*)d_in[0];
    const float* f1    = (const float*)d_in[1];
    const float* f2    = (const float*)d_in[2];
    const float* f3    = (const float*)d_in[3];
    const float* boxes = (const float*)d_in[4];
    float* out         = (float*)d_out;

    roi_align_tap16_kernel<<<NROI * 16, 256, 0, stream>>>(f0, f1, f2, f3, boxes, out);
}